// Round 6
// baseline (628.829 us; speedup 1.0000x reference)
//
#include <hip/hip_runtime.h>
#include <hip/hip_bf16.h>

#define Tt 128
#define Nn 2048
#define Hh 128
#define Dd 128
#define NB 8          // batch rows per block
#define LDA 136       // bf16 LDS row stride (shorts): 128 + 8 pad
#define LDG 388       // fp32 LDS row stride (dwords): 384 + 4 pad

typedef __attribute__((ext_vector_type(8))) short v8s;
typedef __attribute__((ext_vector_type(4))) float v4f;

__device__ __forceinline__ unsigned short f2bf(float f) {
    unsigned int u = __builtin_bit_cast(unsigned int, f);
    u += 0x7FFFu + ((u >> 16) & 1u);   // round-to-nearest-even
    return (unsigned short)(u >> 16);
}

__device__ __forceinline__ v4f mfma_bf(v8s a, v8s b, v4f c) {
    return __builtin_amdgcn_mfma_f32_16x16x32_bf16(a, b, c, 0, 0, 0);
}

__device__ __forceinline__ v8s load_wfrag_bf(const float* __restrict__ W, int row, int k0) {
    const v4f* p = (const v4f*)(W + row * 128 + k0);
    v4f a = p[0], b = p[1];
    v8s r;
    r[0] = (short)f2bf(a[0]); r[1] = (short)f2bf(a[1]);
    r[2] = (short)f2bf(a[2]); r[3] = (short)f2bf(a[3]);
    r[4] = (short)f2bf(b[0]); r[5] = (short)f2bf(b[1]);
    r[6] = (short)f2bf(b[2]); r[7] = (short)f2bf(b[3]);
    return r;
}

__device__ __forceinline__ void store_bf4(unsigned short* p, v4f v) {
    unsigned int lo = ((unsigned int)f2bf(v[1]) << 16) | (unsigned int)f2bf(v[0]);
    unsigned int hi = ((unsigned int)f2bf(v[3]) << 16) | (unsigned int)f2bf(v[2]);
    uint2 d; d.x = lo; d.y = hi;
    *(uint2*)p = d;   // 8B aligned (col4*2 bytes multiple of 8)
}

__device__ __forceinline__ float sigm(float x) { return __frcp_rn(1.f + __expf(-x)); }
__device__ __forceinline__ float tanh_f(float x) {
    return 2.f * __frcp_rn(1.f + __expf(-2.f * x)) - 1.f;
}

// 512 threads = 8 waves, 2-deep software pipeline, 3 barriers/step.
//   P = waves 0-3: holds W1 (wreg[0..1]) + Wih (wreg[2..7])
//   Q = waves 4-7: holds W2 (wreg[0..1]) + Whh (wreg[2..7])
// iter i: segA: P LN1(t=i)        | Q GRU tail(t=i-2)
//         segB: P G1(t=i)->abuf   | Q G2(t=i-1)->bbuf     (same wreg[0..1] code)
//         segC: P gi(t=i-1)->gibuf| Q gh(t=i-1)->ghbuf    (same wreg[2..7] code)
// Numerics bit-identical to the verified R1 kernel (same rounding points).
__global__ __launch_bounds__(512) __attribute__((amdgpu_waves_per_eu(2, 2)))
void rppo_pipe2(const float* __restrict__ x, const float* __restrict__ hxs,
                const float* __restrict__ masks,
                const float* __restrict__ ln1_w, const float* __restrict__ ln1_b,
                const float* __restrict__ W1, const float* __restrict__ b1,
                const float* __restrict__ W2, const float* __restrict__ b2,
                const float* __restrict__ Wih, const float* __restrict__ bih,
                const float* __restrict__ Whh, const float* __restrict__ bhh,
                const float* __restrict__ ln2_w, const float* __restrict__ ln2_b,
                float* __restrict__ out)
{
    __shared__ unsigned short fbuf[8 * LDA];      // LN1 out (A of G1)
    __shared__ unsigned short abuf[2][8 * LDA];   // G1 out, double-buffered by t parity
    __shared__ unsigned short bbuf[8 * LDA];      // G2 out (A of gi)
    __shared__ unsigned short hbuf[8 * LDA];      // masked h (A of gh)
    __shared__ float gibuf[8 * LDG];              // gi + b_ih
    __shared__ float ghbuf[8 * LDG];              // gh + b_hh
    __shared__ float mbuf[Tt * NB];

    const int tid  = threadIdx.x;
    const int wave = tid >> 6;
    const int lane = tid & 63;
    const int l16  = lane & 15;
    const int quad = lane >> 4;
    const int arow = l16 & 7;          // A-frag row (rows 8-15 of M=16 tile are dupes)
    const int wsub = wave & 3;
    const bool isP = (wave < 4);
    const int n0   = blockIdx.x * NB;

    // ---- weight fragments: 128 VGPRs/wave, balanced P/Q ----
    v8s wreg[8][4];
    float brAB[2], brC[6];
    {
        const float* Wab = isP ? W1 : W2;
        const float* bab = isP ? b1 : b2;
        const float* Wc  = isP ? Wih : Whh;
        const float* bc  = isP ? bih : bhh;
#pragma unroll
        for (int c = 0; c < 2; ++c) {
            int rowc = (2 * wsub + c) * 16 + l16;
            brAB[c] = bab[rowc];
#pragma unroll
            for (int kk = 0; kk < 4; ++kk)
                wreg[c][kk] = load_wfrag_bf(Wab, rowc, kk * 32 + quad * 8);
        }
#pragma unroll
        for (int c = 0; c < 6; ++c) {
            int rowc = (6 * wsub + c) * 16 + l16;
            brC[c] = bc[rowc];
#pragma unroll
            for (int kk = 0; kk < 4; ++kk)
                wreg[2 + c][kk] = load_wfrag_bf(Wc, rowc, kk * 32 + quad * 8);
        }
    }

    for (int i = tid; i < Tt * NB; i += 512) {
        int t = i >> 3, b = i & 7;
        mbuf[i] = masks[t * Nn + n0 + b];
    }

    // ---- per-stream elementwise mappings ----
    const int col4 = (tid & 31) << 2;
    const int row8 = tid >> 5;                       // P LN1 row (tid<256)
    const int prow = (wave - 4) * 2 + (lane >> 5);   // Q tail row

    v4f ln1w, ln1b, ln2w, ln2b, h, xv;
    if (isP) {
        ln1w = *(const v4f*)(ln1_w + col4);
        ln1b = *(const v4f*)(ln1_b + col4);
        xv = *(const v4f*)(x + (size_t)(n0 + row8) * Dd + col4);   // t=0 prefetch
    } else {
        ln2w = *(const v4f*)(ln2_w + col4);
        ln2b = *(const v4f*)(ln2_b + col4);
        h = *(const v4f*)(hxs + (size_t)(n0 + prow) * Hh + col4);
        h *= masks[n0 + prow];                       // h entering t=0
        store_bf4(hbuf + prow * LDA + col4, h);
    }
    __syncthreads();

    for (int i = 0; i <= Tt + 1; ++i) {
        // ===== segA: P LN1(t=i) | Q tail(t=i-2) =====
        if (isP) {
            if (i < Tt) {
                float s  = xv[0] + xv[1] + xv[2] + xv[3];
                float ss = xv[0]*xv[0] + xv[1]*xv[1] + xv[2]*xv[2] + xv[3]*xv[3];
#pragma unroll
                for (int m = 1; m < 32; m <<= 1) {
                    s  += __shfl_xor(s,  m, 64);
                    ss += __shfl_xor(ss, m, 64);
                }
                float mu = s * (1.f / 128.f);
                float rs = __frsqrt_rn(ss * (1.f / 128.f) - mu * mu + 1e-5f);
                v4f f;
#pragma unroll
                for (int e = 0; e < 4; ++e) f[e] = (xv[e] - mu) * rs * ln1w[e] + ln1b[e];
                store_bf4(fbuf + row8 * LDA + col4, f);
                if (i + 1 < Tt)
                    xv = *(const v4f*)(x + ((size_t)(i + 1) * Nn + n0 + row8) * Dd + col4);
            }
        } else if (i >= 2) {
            const int t = i - 2;
            const float* gb = gibuf + prow * LDG + col4;
            const float* hb = ghbuf + prow * LDG + col4;
            v4f ir  = *(const v4f*)(gb);
            v4f iz  = *(const v4f*)(gb + 128);
            v4f inn = *(const v4f*)(gb + 256);
            v4f hr  = *(const v4f*)(hb);
            v4f hz  = *(const v4f*)(hb + 128);
            v4f hn  = *(const v4f*)(hb + 256);
            v4f hnew;
#pragma unroll
            for (int e = 0; e < 4; ++e) {
                float r = sigm(ir[e] + hr[e]);
                float z = sigm(iz[e] + hz[e]);
                float n = tanh_f(inn[e] + r * hn[e]);
                hnew[e] = n + z * (h[e] - n);   // (1-z)*n + z*h
            }
            float s2  = hnew[0] + hnew[1] + hnew[2] + hnew[3];
            float ss2 = hnew[0]*hnew[0] + hnew[1]*hnew[1] + hnew[2]*hnew[2] + hnew[3]*hnew[3];
#pragma unroll
            for (int m = 1; m < 32; m <<= 1) {
                s2  += __shfl_xor(s2,  m, 64);
                ss2 += __shfl_xor(ss2, m, 64);
            }
            float mu2 = s2 * (1.f / 128.f);
            float rs2 = __frsqrt_rn(ss2 * (1.f / 128.f) - mu2 * mu2 + 1e-5f);
            v4f o;
#pragma unroll
            for (int e = 0; e < 4; ++e) o[e] = (hnew[e] - mu2) * rs2 * ln2w[e] + ln2b[e];
            *(v4f*)(out + ((size_t)t * Nn + n0 + prow) * Hh + col4) = o;

            if (t + 1 < Tt) {
                float mt = mbuf[(t + 1) * NB + prow];
                h = hnew * mt;                          // h entering step t+1
                store_bf4(hbuf + prow * LDA + col4, h);
            } else {
                *(v4f*)(out + (size_t)Tt * Nn * Hh + (size_t)(n0 + prow) * Hh + col4) = hnew;
            }
        }
        __syncthreads();   // B1

        // ===== segB: P G1(t=i) -> abuf[i&1] | Q G2(t=i-1) -> bbuf =====
        {
            const bool act = isP ? (i < Tt) : (i >= 1 && i <= Tt);
            if (act) {
                const unsigned short* src = isP ? fbuf : abuf[(i + 1) & 1];
                unsigned short* dst = isP ? abuf[i & 1] : bbuf;
                v8s af[4];
#pragma unroll
                for (int kk = 0; kk < 4; ++kk)
                    af[kk] = *(const v8s*)(src + arow * LDA + kk * 32 + quad * 8);
                v4f acc[2] = {{0.f,0.f,0.f,0.f},{0.f,0.f,0.f,0.f}};
#pragma unroll
                for (int c = 0; c < 2; ++c)
#pragma unroll
                    for (int kk = 0; kk < 4; ++kk)
                        acc[c] = mfma_bf(af[kk], wreg[c][kk], acc[c]);
#pragma unroll
                for (int c = 0; c < 2; ++c) {
                    int col = (2 * wsub + c) * 16 + l16;
#pragma unroll
                    for (int rr = 0; rr < 4; ++rr) {
                        int row = quad * 4 + rr;
                        if (row < 8) dst[row * LDA + col] = f2bf(acc[c][rr] + brAB[c]);
                    }
                }
            }
        }
        __syncthreads();   // B2

        // ===== segC: P gi(t=i-1) -> gibuf | Q gh(t=i-1) -> ghbuf =====
        if (i >= 1 && i <= Tt) {
            const unsigned short* src = isP ? bbuf : hbuf;
            float* dst = isP ? gibuf : ghbuf;
            v8s af[4];
#pragma unroll
            for (int kk = 0; kk < 4; ++kk)
                af[kk] = *(const v8s*)(src + arow * LDA + kk * 32 + quad * 8);
            v4f acc[6];
#pragma unroll
            for (int c = 0; c < 6; ++c) acc[c] = (v4f){0.f,0.f,0.f,0.f};
#pragma unroll
            for (int c = 0; c < 6; ++c)
#pragma unroll
                for (int kk = 0; kk < 4; ++kk)
                    acc[c] = mfma_bf(af[kk], wreg[2 + c][kk], acc[c]);
#pragma unroll
            for (int c = 0; c < 6; ++c) {
                int col = (6 * wsub + c) * 16 + l16;
#pragma unroll
                for (int rr = 0; rr < 4; ++rr) {
                    int row = quad * 4 + rr;
                    if (row < 8) dst[row * LDG + col] = acc[c][rr] + brC[c];
                }
            }
        }
        __syncthreads();   // B3
    }
}

extern "C" void kernel_launch(void* const* d_in, const int* in_sizes, int n_in,
                              void* d_out, int out_size, void* d_ws, size_t ws_size,
                              hipStream_t stream) {
    const float* x     = (const float*)d_in[0];
    const float* hxs   = (const float*)d_in[1];
    const float* masks = (const float*)d_in[2];
    const float* ln1w  = (const float*)d_in[3];
    const float* ln1b  = (const float*)d_in[4];
    const float* W1    = (const float*)d_in[5];
    const float* b1    = (const float*)d_in[6];
    const float* W2    = (const float*)d_in[7];
    const float* b2    = (const float*)d_in[8];
    const float* Wih   = (const float*)d_in[9];
    const float* bih   = (const float*)d_in[10];
    const float* Whh   = (const float*)d_in[11];
    const float* bhh   = (const float*)d_in[12];
    const float* ln2w  = (const float*)d_in[13];
    const float* ln2b  = (const float*)d_in[14];
    float* out = (float*)d_out;

    hipLaunchKernelGGL(rppo_pipe2, dim3(Nn / NB), dim3(512), 0, stream,
                       x, hxs, masks, ln1w, ln1b, W1, b1, W2, b2,
                       Wih, bih, Whh, bhh, ln2w, ln2b, out);
}